// Round 7
// baseline (243.394 us; speedup 1.0000x reference)
//
#include <hip/hip_runtime.h>

typedef _Float16 f16;
typedef _Float16 f16x4 __attribute__((ext_vector_type(4)));
typedef _Float16 f16x8 __attribute__((ext_vector_type(8)));
typedef float    f32x4 __attribute__((ext_vector_type(4)));

#define MFMA(a,b,c) __builtin_amdgcn_mfma_f32_16x16x32_f16(a,b,c,0,0,0)

#if __has_builtin(__builtin_amdgcn_exp2f)
#define EXP2(x) __builtin_amdgcn_exp2f(x)
#else
#define EXP2(x) exp2f(x)
#endif

#define SBAR() __builtin_amdgcn_sched_barrier(0)

__device__ __forceinline__ void gld16(const void* g, void* l) {
  typedef __attribute__((address_space(1))) unsigned GU;
  typedef __attribute__((address_space(3))) unsigned LU;
  __builtin_amdgcn_global_load_lds((GU*)g, (LU*)l, 16, 0, 0);
}

// ---------------- K0: weight transpose via LDS tiles ----------------
__global__ __launch_bounds__(256) void transp_w(
    const float* __restrict__ Wq, const float* __restrict__ Wk,
    const float* __restrict__ Wv, const float* __restrict__ Wo,
    f16* __restrict__ Wqt, f16* __restrict__ Wkt, f16* __restrict__ Wvt,
    f16* __restrict__ Wot)
{
  __shared__ float T[64 * 65];
  int bid = blockIdx.x, t = threadIdx.x;
  int mat = bid >> 6;
  int i0 = (bid & 7) * 64, c0 = ((bid >> 3) & 7) * 64;
  const float* src; f16* dst; float scale = 1.f;
  if      (mat == 0) { src = Wq; dst = Wqt; scale = 0.125f * 1.4426950408889634f; }
  else if (mat == 1) { src = Wk; dst = Wkt; }
  else if (mat == 2) { src = Wv; dst = Wvt; }
  else               { src = Wo; dst = Wot; }
#pragma unroll
  for (int p = 0; p < 4; ++p) {
    int row = p * 16 + (t >> 4), col = (t & 15) * 4;
    const float* a = (mat < 3)
        ? src + ((c0 >> 6) * 512 + i0 + row) * 64 + col
        : src + (i0 + row) * 512 + c0 + col;
    f32x4 v = *(const f32x4*)a;
    T[row * 65 + col + 0] = v[0] * scale;
    T[row * 65 + col + 1] = v[1] * scale;
    T[row * 65 + col + 2] = v[2] * scale;
    T[row * 65 + col + 3] = v[3] * scale;
  }
  __syncthreads();
#pragma unroll
  for (int p = 0; p < 16; ++p) {
    int cc = (t >> 6) * 16 + p, ii = t & 63;
    dst[(c0 + cc) * 512 + i0 + ii] = (f16)T[ii * 65 + cc];
  }
}

// ---------------- K1: QKV projection — R4 tiling + counted-vmcnt pipeline ----
// Identical maps/epilogue to R4 (conflict-free verified). New k-loop:
// raw s_barrier (no compiler vmcnt(0) drain), A fp32 loads 2 steps ahead
// (two reg banks), B gld_lds 1 step ahead, per-step s_waitcnt vmcnt(4)
// (waits only B(k+1); A(k+2) stays in flight). Order pinned by sched_barrier.
__global__ __launch_bounds__(256, 3) void proj_kernel(
    const float* __restrict__ q,
    const f16* __restrict__ Wqt, const f16* __restrict__ Wkt, const f16* __restrict__ Wvt,
    f16* __restrict__ Qh, f16* __restrict__ Kh, f16* __restrict__ Vtb)
{
  __shared__ f16 Asl[2][4096];
  __shared__ f16 Bsl[2][4096];

  int bid0 = blockIdx.x;
  int tile = (bid0 & 7) * 240 + (bid0 >> 3);   // XCD-chunked, bijective (1920=8*240)

  int tid = threadIdx.x, l = tid & 63, w = tid >> 6;
  int wr = w >> 1, wc = w & 1;

  bool qmode = tile < 128;
  int rt, colbase, vmode = 0;
  const f16* Wt;
  if (qmode) {
    rt = tile >> 2; colbase = (tile & 3) * 128; Wt = Wqt;
  } else {
    int t2 = tile - 128; rt = t2 >> 3; int cc = t2 & 7;
    if (cc < 4) { Wt = Wkt; colbase = cc * 128; }
    else        { Wt = Wvt; colbase = (cc - 4) * 128; vmode = 1; }
  }
  int gbase, bidx;
  if (qmode) { bidx = rt >> 2; gbase = bidx * 4096 + (rt & 3) * 128; }
  else       { bidx = rt / 28; gbase = bidx * 4096 + 512 + (rt * 128 - bidx * 3584); }

  // B staging map (global_load_lds, inverse-swizzled source)
  const f16* bsrc[2];
  int ldst[2];
#pragma unroll
  for (int j = 0; j < 2; ++j) {
    int s = tid + j * 256;
    int r = s >> 2;
    int c = (s & 3) ^ ((r >> 1) & 3);
    bsrc[j] = Wt + (size_t)(colbase + r) * 512 + c * 8;
    ldst[j] = (j * 256 + w * 64) * 8;
  }
  // A ds_write map: thread row r=tid>>1, chunks {2h,2h+1}, h=tid&1
  int awrow = tid >> 1, awh = tid & 1;
  int awo0 = awrow * 64 + (((awh * 2 + 0) ^ ((awrow >> 1) & 3)) << 4);
  int awo1 = awrow * 64 + (((awh * 2 + 1) ^ ((awrow >> 1) & 3)) << 4);
  const float* awsrc = q + (size_t)(gbase + awrow) * 512 + awh * 16;

  // frag read byte offsets
  int aro[4], bro[4];
#pragma unroll
  for (int i = 0; i < 4; ++i) {
    int ra = wr * 64 + i * 16 + (l & 15);
    aro[i] = ra * 64 + ((((l >> 4)) ^ ((ra >> 1) & 3)) << 4);
    int rb = wc * 64 + i * 16 + (l & 15);
    bro[i] = rb * 64 + ((((l >> 4)) ^ ((rb >> 1) & 3)) << 4);
  }

  const f32x4 z4 = {0.f, 0.f, 0.f, 0.f};
  f32x4 acc[4][4];
#pragma unroll
  for (int i = 0; i < 4; ++i)
#pragma unroll
    for (int j = 0; j < 4; ++j) acc[i][j] = z4;

  f32x4 ar[2][4];   // two A prefetch banks (indices compile-time after unroll)

  auto awrite = [&](int bank, int bufi) {
    f16x8 h0, h1;
#pragma unroll
    for (int e = 0; e < 4; ++e) {
      h0[e] = (f16)ar[bank][0][e]; h0[4 + e] = (f16)ar[bank][1][e];
      h1[e] = (f16)ar[bank][2][e]; h1[4 + e] = (f16)ar[bank][3][e];
    }
    *(f16x8*)((char*)&Asl[bufi][0] + awo0) = h0;
    *(f16x8*)((char*)&Asl[bufi][0] + awo1) = h1;
  };

  // ---- prologue ----
#pragma unroll
  for (int i = 0; i < 4; ++i) ar[0][i] = *(const f32x4*)(awsrc + i * 4);
  SBAR();
  awrite(0, 0);                       // compiler waits A(0) regs
  SBAR();
  gld16(bsrc[0], &Bsl[0][ldst[0]]);   // B(0)
  gld16(bsrc[1], &Bsl[0][ldst[1]]);
  SBAR();
#pragma unroll
  for (int i = 0; i < 4; ++i) ar[1][i] = *(const f32x4*)(awsrc + 32 + i * 4);  // A(1)
  SBAR();
  asm volatile("s_waitcnt vmcnt(4) lgkmcnt(0)" ::: "memory");  // B(0) landed; A(1) in flight
  __builtin_amdgcn_s_barrier();
  SBAR();

  // ---- main loop (fully unrolled; ks compile-time) ----
#pragma unroll
  for (int ks = 0; ks < 16; ++ks) {
    const int cur = ks & 1;
    if (ks < 15) {                    // B(k+1) -> other buffer (last read at k-1)
      gld16(bsrc[0] + (ks + 1) * 32, &Bsl[cur ^ 1][ldst[0]]);
      gld16(bsrc[1] + (ks + 1) * 32, &Bsl[cur ^ 1][ldst[1]]);
    }
    SBAR();
    if (ks < 14) {                    // A(k+2) -> bank cur (consumed at ks+1)
#pragma unroll
      for (int i = 0; i < 4; ++i)
        ar[cur][i] = *(const f32x4*)(awsrc + (ks + 2) * 32 + i * 4);
    }
    SBAR();
    {
      const char* AB = (const char*)&Asl[cur][0];
      const char* BB = (const char*)&Bsl[cur][0];
      f16x8 af[4], bf[4];
#pragma unroll
      for (int i = 0; i < 4; ++i) af[i] = *(const f16x8*)(AB + aro[i]);
#pragma unroll
      for (int i = 0; i < 4; ++i) bf[i] = *(const f16x8*)(BB + bro[i]);
#pragma unroll
      for (int mi = 0; mi < 4; ++mi)
#pragma unroll
        for (int ni = 0; ni < 4; ++ni)
          acc[mi][ni] = MFMA(af[mi], bf[ni], acc[mi][ni]);
    }
    SBAR();
    if (ks < 15) {
      awrite(cur ^ 1, cur ^ 1);       // cvt A(k+1) (compiler-inserted vmcnt wait)
      SBAR();
      if (ks < 14) asm volatile("s_waitcnt vmcnt(4) lgkmcnt(0)" ::: "memory");
      else         asm volatile("s_waitcnt vmcnt(0) lgkmcnt(0)" ::: "memory");
      __builtin_amdgcn_s_barrier();
      SBAR();
    }
  }

  // ---- epilogue (unchanged from R4) ----
  if (qmode) {
#pragma unroll
    for (int mi = 0; mi < 4; ++mi) {
      int row = rt * 128 + wr * 64 + mi * 16 + (l >> 4) * 4;
#pragma unroll
      for (int ni = 0; ni < 4; ++ni) {
        int col = colbase + wc * 64 + ni * 16 + (l & 15);
#pragma unroll
        for (int r = 0; r < 4; ++r)
          Qh[(size_t)(row + r) * 512 + col] = (f16)acc[mi][ni][r];
      }
    }
  } else if (!vmode) {
#pragma unroll
    for (int mi = 0; mi < 4; ++mi) {
      int row = rt * 128 + wr * 64 + mi * 16 + (l >> 4) * 4;
#pragma unroll
      for (int ni = 0; ni < 4; ++ni) {
        int col = colbase + wc * 64 + ni * 16 + (l & 15);
#pragma unroll
        for (int r = 0; r < 4; ++r)
          Kh[(size_t)(row + r) * 512 + col] = (f16)acc[mi][ni][r];
      }
    }
  } else {
    int g0 = rt * 128 - bidx * 3584;
#pragma unroll
    for (int mi = 0; mi < 4; ++mi) {
      int g = g0 + wr * 64 + mi * 16 + (l >> 4) * 4;
#pragma unroll
      for (int ni = 0; ni < 4; ++ni) {
        int c4 = colbase + wc * 64 + ni * 16 + (l & 15);
        int hh = c4 >> 6, v = c4 & 63;
        f16x4 o4;
        o4[0] = (f16)acc[mi][ni][0]; o4[1] = (f16)acc[mi][ni][1];
        o4[2] = (f16)acc[mi][ni][2]; o4[3] = (f16)acc[mi][ni][3];
        *(f16x4*)(Vtb + (size_t)((bidx * 8 + hh) * 64 + v) * 3584 + g) = o4;
      }
    }
  }
}

// ---------------- K2: flash attention, split-KV x4, swapped-QK^T -------------
// grid 1024: seg=bid&3 (896 tokens each), qt=(bid>>2)&3, h=(bid>>4)&7, bb=bid>>7
__global__ __launch_bounds__(512, 4) void attn_kernel(
    const f16* __restrict__ Qh, const f16* __restrict__ Kh,
    const f16* __restrict__ Vtb, f16* __restrict__ Opart,
    float* __restrict__ Ml, float* __restrict__ Ll)
{
  __shared__ f16 Klds[2][4096];
  __shared__ f16 Vlds[2][4096];
  __shared__ f16 Plds[8 * 1152];

  int bid = blockIdx.x;
  int seg = bid & 3, qt = (bid >> 2) & 3, h = (bid >> 4) & 7, bb = bid >> 7;
  int q0 = qt * 128;
  int tid = threadIdx.x, l = tid & 63, w = tid >> 6;

  f16x8 qf0, qf1;
  {
    int qrow = q0 + w * 16 + (l & 15);
    const f16* qb = Qh + (bb * 512 + qrow) * 512 + h * 64 + ((l >> 4) * 8);
    qf0 = *(const f16x8*)qb;
    qf1 = *(const f16x8*)(qb + 32);
  }

  bool isK = (w < 4);
  int sdo[2], ssrc[2];
#pragma unroll
  for (int j = 0; j < 2; ++j) {
    int id = (isK ? w : (w - 4)) * 2 + j;
    int rr = id * 8 + (l >> 3);
    int co = ((l & 7) ^ (rr & 7)) * 8;
    sdo[j] = id * 512;
    if (isK) ssrc[j] = (bb * 3584 + seg * 896 + rr) * 512 + h * 64 + co;
    else     ssrc[j] = ((bb * 8 + h) * 64 + rr) * 3584 + seg * 896 + co;
  }

  const f32x4 z4 = {0.f, 0.f, 0.f, 0.f};
  f32x4 acco[4];
#pragma unroll
  for (int i = 0; i < 4; ++i) acco[i] = z4;
  float mrow = -1e30f, lrow = 0.f;

  char* PwB = (char*)&Plds[w * 1152];
  int pwbase = (l & 15) * 144 + (l >> 4) * 8;
  int prbase = (l & 15) * 144 + (l >> 4) * 16;

  if (isK) { gld16(Kh + ssrc[0], &Klds[0][sdo[0]]); gld16(Kh + ssrc[1], &Klds[0][sdo[1]]); }
  else     { gld16(Vtb + ssrc[0], &Vlds[0][sdo[0]]); gld16(Vtb + ssrc[1], &Vlds[0][sdo[1]]); }
  __syncthreads();

  int buf = 0;
  for (int it = 0; it < 14; ++it) {
    if (it < 13) {
      int g0 = (it + 1) * 64;
      if (isK) { gld16(Kh + ssrc[0] + g0 * 512, &Klds[buf ^ 1][sdo[0]]);
                 gld16(Kh + ssrc[1] + g0 * 512, &Klds[buf ^ 1][sdo[1]]); }
      else     { gld16(Vtb + ssrc[0] + g0, &Vlds[buf ^ 1][sdo[0]]);
                 gld16(Vtb + ssrc[1] + g0, &Vlds[buf ^ 1][sdo[1]]); }
    }
    const char* KB = (const char*)&Klds[buf][0];
    const char* VB = (const char*)&Vlds[buf][0];

    f32x4 accs[4];
#pragma unroll
    for (int i = 0; i < 4; ++i) accs[i] = z4;
#pragma unroll
    for (int ni = 0; ni < 4; ++ni) {
      int g = ni * 16 + (l & 15);
      const char* rp = KB + g * 128;
      f16x8 k0 = *(const f16x8*)(rp + ((((l >> 4)    ) ^ (g & 7)) << 4));
      f16x8 k1 = *(const f16x8*)(rp + (((4 + (l >> 4)) ^ (g & 7)) << 4));
      accs[ni] = MFMA(k0, qf0, accs[ni]);
      accs[ni] = MFMA(k1, qf1, accs[ni]);
    }

    float n0 = fmaxf(fmaxf(accs[0][0], accs[0][1]), fmaxf(accs[0][2], accs[0][3]));
    float n1 = fmaxf(fmaxf(accs[1][0], accs[1][1]), fmaxf(accs[1][2], accs[1][3]));
    float n2 = fmaxf(fmaxf(accs[2][0], accs[2][1]), fmaxf(accs[2][2], accs[2][3]));
    float n3 = fmaxf(fmaxf(accs[3][0], accs[3][1]), fmaxf(accs[3][2], accs[3][3]));
    float tm = fmaxf(fmaxf(n0, n1), fmaxf(n2, n3));
    tm = fmaxf(tm, __shfl_xor(tm, 16));
    tm = fmaxf(tm, __shfl_xor(tm, 32));
    float mn = fmaxf(mrow, tm);
    float alpha = EXP2(mrow - mn);
    mrow = mn;

    float rs = 0.f;
#pragma unroll
    for (int ni = 0; ni < 4; ++ni) {
      float s0 = EXP2(accs[ni][0] - mrow);
      float s1 = EXP2(accs[ni][1] - mrow);
      float s2 = EXP2(accs[ni][2] - mrow);
      float s3 = EXP2(accs[ni][3] - mrow);
      rs += (s0 + s1) + (s2 + s3);
      f16x4 p4;
      p4[0] = (f16)s0; p4[1] = (f16)s1; p4[2] = (f16)s2; p4[3] = (f16)s3;
      *(f16x4*)(PwB + pwbase + ni * 32) = p4;
    }
    rs += __shfl_xor(rs, 16);
    rs += __shfl_xor(rs, 32);
    lrow = lrow * alpha + rs;
#pragma unroll
    for (int ni = 0; ni < 4; ++ni)
#pragma unroll
      for (int r = 0; r < 4; ++r) acco[ni][r] *= alpha;

    asm volatile("s_waitcnt lgkmcnt(0)" ::: "memory");

#pragma unroll
    for (int kc = 0; kc < 2; ++kc) {
      f16x8 pf = *(const f16x8*)(PwB + prbase + kc * 64);
#pragma unroll
      for (int ni = 0; ni < 4; ++ni) {
        int v = ni * 16 + (l & 15);
        f16x8 vf = *(const f16x8*)(VB + v * 128 + (((kc * 4 + (l >> 4)) ^ (v & 7)) << 4));
        acco[ni] = MFMA(vf, pf, acco[ni]);
      }
    }

    __syncthreads();
    buf ^= 1;
  }

  float inv = 1.f / lrow;
  int q = q0 + w * 16 + (l & 15);
  size_t obase = ((size_t)(seg * 64 + bb * 8 + h) * 512 + q) * 64;
#pragma unroll
  for (int ni = 0; ni < 4; ++ni) {
    f16x4 o4;
    o4[0] = (f16)(acco[ni][0] * inv); o4[1] = (f16)(acco[ni][1] * inv);
    o4[2] = (f16)(acco[ni][2] * inv); o4[3] = (f16)(acco[ni][3] * inv);
    *(f16x4*)(Opart + obase + ni * 16 + (l >> 4) * 4) = o4;
  }
  if ((l >> 4) == 0) {
    int mi = (seg * 64 + bb * 8 + h) * 512 + q;
    Ml[mi] = mrow; Ll[mi] = lrow;
  }
}

// ---------------- K2b: merge the four KV segments ----------------
__global__ __launch_bounds__(256) void merge_kernel(
    const f16* __restrict__ Opart, const float* __restrict__ Ml,
    const float* __restrict__ Ll, f16* __restrict__ Hm)
{
  int row = blockIdx.x * 4 + (threadIdx.x >> 6);
  int l = threadIdx.x & 63;
  int bh = row >> 9, q = row & 511;
  int idx[4];
  float ms[4], ls[4], os[4];
#pragma unroll
  for (int s = 0; s < 4; ++s) {
    idx[s] = (s * 64 + bh) * 512 + q;
    ms[s] = Ml[idx[s]]; ls[s] = Ll[idx[s]];
    os[s] = (float)Opart[(size_t)idx[s] * 64 + l];
  }
  float m = fmaxf(fmaxf(ms[0], ms[1]), fmaxf(ms[2], ms[3]));
  float num = 0.f, den = 0.f;
#pragma unroll
  for (int s = 0; s < 4; ++s) {
    float ws = EXP2(ms[s] - m) * ls[s];
    num += ws * os[s]; den += ws;
  }
  int bb = bh >> 3, hh = bh & 7;
  Hm[((size_t)(bb * 512 + q)) * 512 + hh * 64 + l] = (f16)(num / den);
}

// ---------------- K3: output projection GEMM ----------------
__global__ __launch_bounds__(256) void outproj_kernel(
    const f16* __restrict__ Hm, const f16* __restrict__ Wot, float* __restrict__ out)
{
  __shared__ f16 Asl[2][4096];
  __shared__ f16 Bsl[2][4096];
  int bid = blockIdx.x;
  int rt = bid >> 2, ct = bid & 3;
  int tid = threadIdx.x, l = tid & 63, w = tid >> 6;
  int m0 = rt * 128, n0 = ct * 128;
  int wr = w >> 1, wc = w & 1;

  int an[2], aco[2];
#pragma unroll
  for (int j = 0; j < 2; ++j) {
    int r = (w * 2 + j) * 16 + (l >> 2);
    an[j] = r;
    aco[j] = ((l & 3) ^ (r & 3)) * 8;
  }

  const f32x4 z4 = {0.f, 0.f, 0.f, 0.f};
  f32x4 acc[4][4];
#pragma unroll
  for (int i = 0; i < 4; ++i)
#pragma unroll
    for (int jj = 0; jj < 4; ++jj) acc[i][jj] = z4;

  auto stage = [&](int bufi, int k0) {
#pragma unroll
    for (int j = 0; j < 2; ++j) {
      gld16(Hm  + (m0 + an[j]) * 512 + k0 + aco[j], &Asl[bufi][(w * 2 + j) * 512]);
      gld16(Wot + (n0 + an[j]) * 512 + k0 + aco[j], &Bsl[bufi][(w * 2 + j) * 512]);
    }
  };

  stage(0, 0);
  __syncthreads();
  for (int ks = 0; ks < 16; ++ks) {
    int bufi = ks & 1;
    if (ks < 15) stage(bufi ^ 1, (ks + 1) * 32);
    const char* AB = (const char*)&Asl[bufi][0];
    const char* BB = (const char*)&Bsl[bufi][0];
    f16x8 af[4], bf[4];
#pragma unroll
    for (int mi = 0; mi < 4; ++mi) {
      int row = wr * 64 + mi * 16 + (l & 15);
      af[mi] = *(const f16x8*)(AB + row * 64 + (((l >> 4) ^ (row & 3)) << 4));
    }
#pragma unroll
    for (int ni = 0; ni < 4; ++ni) {
      int rn = wc * 64 + ni * 16 + (l & 15);
      bf[ni] = *(const f16x8*)(BB + rn * 64 + (((l >> 4) ^ (rn & 3)) << 4));
    }
#pragma unroll
    for (int mi = 0; mi < 4; ++mi)
#pragma unroll
      for (int ni = 0; ni < 4; ++ni)
        acc[mi][ni] = MFMA(af[mi], bf[ni], acc[mi][ni]);
    __syncthreads();
  }

#pragma unroll
  for (int mi = 0; mi < 4; ++mi) {
    int row = m0 + wr * 64 + mi * 16 + (l >> 4) * 4;
#pragma unroll
    for (int ni = 0; ni < 4; ++ni) {
      int col = n0 + wc * 64 + ni * 16 + (l & 15);
#pragma unroll
      for (int r = 0; r < 4; ++r)
        out[(row + r) * 512 + col] = acc[mi][ni][r];
    }
  }
}

extern "C" void kernel_launch(void* const* d_in, const int* in_sizes, int n_in,
                              void* d_out, int out_size, void* d_ws, size_t ws_size,
                              hipStream_t stream) {
  const float* q  = (const float*)d_in[0];
  const float* Wq = (const float*)d_in[1];
  const float* Wk = (const float*)d_in[2];
  const float* Wv = (const float*)d_in[3];
  const float* Wo = (const float*)d_in[4];
  float* out = (float*)d_out;

  f16* ws  = (f16*)d_ws;
  f16* Wqt = ws;                        // 262144
  f16* Wkt = Wqt + 262144;
  f16* Wvt = Wkt + 262144;
  f16* Wot = Wvt + 262144;
  f16* Qh  = Wot + 262144;              // 4096*512
  f16* Kh  = Qh  + 4096 * 512;          // 28672*512
  f16* Vtb = Kh  + 28672 * 512;         // 28672*512 (transposed V)
  f16* Opart = Vtb + 28672 * 512;       // 4*64*512*64 (segment-normalized O^T)
  float* Ml = (float*)(Opart + (size_t)4 * 64 * 512 * 64);  // 4*64*512
  float* Ll = Ml + 131072;
  f16* Hm = Qh;                         // reuse: attn done before merge writes

  transp_w<<<dim3(256),  dim3(256), 0, stream>>>(Wq, Wk, Wv, Wo, Wqt, Wkt, Wvt, Wot);
  proj_kernel<<<dim3(1920), dim3(256), 0, stream>>>(q, Wqt, Wkt, Wvt, Qh, Kh, Vtb);
  attn_kernel<<<dim3(1024), dim3(512), 0, stream>>>(Qh, Kh, Vtb, Opart, Ml, Ll);
  merge_kernel<<<dim3(8192), dim3(256), 0, stream>>>(Opart, Ml, Ll, Hm);
  outproj_kernel<<<dim3(128), dim3(256), 0, stream>>>(Hm, Wot, out);
}